// Round 1
// baseline (10425.893 us; speedup 1.0000x reference)
//
#include <hip/hip_runtime.h>
#include <cstdint>
#include <cstddef>

#define HW_NRAYS 16384
#define NSAMP    (1 << 21)
#define NLEV     12
#define TSZ      (1 << 19)
#define TMASK    (TSZ - 1)
#define DIN      24
#define HDIM     32

__device__ __forceinline__ float clamp01f(float v) { return fminf(fmaxf(v, 0.f), 1.f); }

__global__ __launch_bounds__(64)
void ngp_render(const float* __restrict__ rays_o,
                const float* __restrict__ rays_d,
                const float* __restrict__ t_starts,
                const float* __restrict__ t_ends,
                const int*   __restrict__ ray_idx,
                const float* __restrict__ tab_d,
                const float* __restrict__ tab_c,
                const float* __restrict__ w_d1,
                const float* __restrict__ w_d2,
                const float* __restrict__ w_c1,
                const float* __restrict__ w_c2,
                float* __restrict__ out)
{
    __shared__ __align__(16) float s_wd1[DIN * HDIM];
    __shared__ __align__(16) float s_wc1[DIN * HDIM];
    __shared__ __align__(16) float s_wd2[HDIM];
    __shared__ __align__(16) float s_wc2[HDIM * 3];

    const int lane = threadIdx.x;
    for (int i = lane; i < DIN * HDIM; i += 64) { s_wd1[i] = w_d1[i]; s_wc1[i] = w_c1[i]; }
    if (lane < HDIM) s_wd2[lane] = w_d2[lane];
    for (int i = lane; i < HDIM * 3; i += 64) s_wc2[i] = w_c2[i];
    __syncthreads();

    const int r = blockIdx.x;

    // lower_bound(ray_idx, r) and lower_bound(ray_idx, r+1) on sorted array
    int lo = 0, hi = NSAMP;
    while (lo < hi) { int m = (lo + hi) >> 1; if (ray_idx[m] < r) lo = m + 1; else hi = m; }
    const int start = lo;
    hi = NSAMP;
    while (lo < hi) { int m = (lo + hi) >> 1; if (ray_idx[m] <= r) lo = m + 1; else hi = m; }
    const int end = lo;

    const float ox = rays_o[3 * r + 0], oy = rays_o[3 * r + 1], oz = rays_o[3 * r + 2];
    const float dx = rays_d[3 * r + 0], dy = rays_d[3 * r + 1], dz = rays_d[3 * r + 2];

    float carry = 0.f, accw = 0.f, cr = 0.f, cg = 0.f, cb = 0.f;

    for (int base = start; base < end; base += 64) {
        const int i = base + lane;
        const bool valid = i < end;
        float sv = 0.f, R = 0.f, G = 0.f, B = 0.f;
        if (valid) {
            const float ts = t_starts[i], te = t_ends[i];
            const float tm = 0.5f * (ts + te);
            const float x01x = clamp01f((ox + dx * tm + 1.f) * 0.5f);
            const float x01y = clamp01f((oy + dy * tm + 1.f) * 0.5f);
            const float x01z = clamp01f((oz + dz * tm + 1.f) * 0.5f);

            float fd[DIN], fc[DIN];
            #pragma unroll
            for (int l = 0; l < NLEV; ++l) {
                const float res1 = (float)((16 << l) - 1);
                const float px = x01x * res1, py = x01y * res1, pz = x01z * res1;
                const float fxf = floorf(px), fyf = floorf(py), fzf = floorf(pz);
                const uint32_t ix = (uint32_t)fxf, iy = (uint32_t)fyf, iz = (uint32_t)fzf;
                const float fx = px - fxf, fy = py - fyf, fz = pz - fzf;
                const uint32_t hx0 = ix, hx1 = ix + 1u;
                const uint32_t hy0 = iy * 2654435761u, hy1 = hy0 + 2654435761u;
                const uint32_t hz0 = iz * 805459861u,  hz1 = hz0 + 805459861u;
                const float wx0 = 1.f - fx, wx1 = fx;
                const float wy0 = 1.f - fy, wy1 = fy;
                const float wz0 = 1.f - fz, wz1 = fz;
                const float* td = tab_d + (size_t)l * (TSZ * 2);
                const float* tc = tab_c + (size_t)l * (TSZ * 2);
                float a0 = 0.f, a1 = 0.f, b0 = 0.f, b1 = 0.f;
                #pragma unroll
                for (int c = 0; c < 8; ++c) {
                    const uint32_t h = ((c & 1) ? hx1 : hx0) ^ ((c & 2) ? hy1 : hy0) ^ ((c & 4) ? hz1 : hz0);
                    const uint32_t idx2 = (h & TMASK) * 2u;
                    const float w = ((c & 1) ? wx1 : wx0) * ((c & 2) ? wy1 : wy0) * ((c & 4) ? wz1 : wz0);
                    const float2 vd = *(const float2*)(td + idx2);
                    const float2 vc = *(const float2*)(tc + idx2);
                    a0 += w * vd.x; a1 += w * vd.y;
                    b0 += w * vc.x; b1 += w * vc.y;
                }
                fd[2 * l] = a0; fd[2 * l + 1] = a1;
                fc[2 * l] = b0; fc[2 * l + 1] = b1;
            }

            // density MLP: 24 -> 32 (relu) -> 1, trunc_exp
            float hb[HDIM];
            #pragma unroll
            for (int j = 0; j < HDIM; ++j) hb[j] = 0.f;
            #pragma unroll
            for (int k = 0; k < DIN; ++k) {
                const float f = fd[k];
                #pragma unroll
                for (int j = 0; j < HDIM; j += 4) {
                    const float4 w = *(const float4*)(s_wd1 + k * HDIM + j);
                    hb[j + 0] += f * w.x; hb[j + 1] += f * w.y;
                    hb[j + 2] += f * w.z; hb[j + 3] += f * w.w;
                }
            }
            float dotv = 0.f;
            #pragma unroll
            for (int j = 0; j < HDIM; ++j) dotv += fmaxf(hb[j], 0.f) * s_wd2[j];
            sv = expf(dotv) * (te - ts);

            // color MLP: 24 -> 32 (relu) -> 3, sigmoid
            #pragma unroll
            for (int j = 0; j < HDIM; ++j) hb[j] = 0.f;
            #pragma unroll
            for (int k = 0; k < DIN; ++k) {
                const float f = fc[k];
                #pragma unroll
                for (int j = 0; j < HDIM; j += 4) {
                    const float4 w = *(const float4*)(s_wc1 + k * HDIM + j);
                    hb[j + 0] += f * w.x; hb[j + 1] += f * w.y;
                    hb[j + 2] += f * w.z; hb[j + 3] += f * w.w;
                }
            }
            float pr = 0.f, pg = 0.f, pb = 0.f;
            #pragma unroll
            for (int j = 0; j < HDIM; ++j) {
                const float hj = fmaxf(hb[j], 0.f);
                pr += hj * s_wc2[3 * j + 0];
                pg += hj * s_wc2[3 * j + 1];
                pb += hj * s_wc2[3 * j + 2];
            }
            R = 1.f / (1.f + expf(-pr));
            G = 1.f / (1.f + expf(-pg));
            B = 1.f / (1.f + expf(-pb));
        }

        // wave-wide inclusive scan of sv (64 lanes)
        float incl = sv;
        #pragma unroll
        for (int off = 1; off < 64; off <<= 1) {
            float t = __shfl_up(incl, off);
            if (lane >= off) incl += t;
        }
        const float e = carry + (incl - sv);      // exclusive cumsum within ray
        const float w = valid ? (1.f - expf(-sv)) * expf(-e) : 0.f;
        accw += w; cr += w * R; cg += w * G; cb += w * B;
        carry += __shfl(incl, 63);
    }

    // wave reduction of the four accumulators
    #pragma unroll
    for (int off = 32; off > 0; off >>= 1) {
        accw += __shfl_down(accw, off);
        cr   += __shfl_down(cr, off);
        cg   += __shfl_down(cg, off);
        cb   += __shfl_down(cb, off);
    }

    if (lane == 0) {
        const float bgw = 1.f - accw;   // BG_COLOR = 1.0
        out[0 * HW_NRAYS + r] = clamp01f(cr + bgw);
        out[1 * HW_NRAYS + r] = clamp01f(cg + bgw);
        out[2 * HW_NRAYS + r] = clamp01f(cb + bgw);
        out[3 * HW_NRAYS + r] = clamp01f(accw);
    }
}

extern "C" void kernel_launch(void* const* d_in, const int* in_sizes, int n_in,
                              void* d_out, int out_size, void* d_ws, size_t ws_size,
                              hipStream_t stream) {
    const float* rays_o        = (const float*)d_in[0];
    const float* rays_d        = (const float*)d_in[1];
    const float* t_starts      = (const float*)d_in[2];
    const float* t_ends        = (const float*)d_in[3];
    const int*   ray_indices   = (const int*)d_in[4];
    const float* table_density = (const float*)d_in[5];
    const float* table_color   = (const float*)d_in[6];
    const float* w_d1          = (const float*)d_in[7];
    const float* w_d2          = (const float*)d_in[8];
    const float* w_c1          = (const float*)d_in[9];
    const float* w_c2          = (const float*)d_in[10];
    float* outp = (float*)d_out;

    hipLaunchKernelGGL(ngp_render, dim3(HW_NRAYS), dim3(64), 0, stream,
                       rays_o, rays_d, t_starts, t_ends, ray_indices,
                       table_density, table_color, w_d1, w_d2, w_c1, w_c2, outp);
}

// Round 2
// 7059.941 us; speedup vs baseline: 1.4768x; 1.4768x over previous
//
#include <hip/hip_runtime.h>
#include <cstdint>
#include <cstddef>

#define HW_NRAYS 16384
#define NSAMP    (1 << 21)
#define NLEV     12
#define TSZ      (1 << 19)
#define TMASK    (TSZ - 1)
#define DIN      24
#define HDIM     32

__device__ __forceinline__ float clamp01f(float v) { return fminf(fmaxf(v, 0.f), 1.f); }

__global__ __launch_bounds__(64, 4)
void ngp_render(const float* __restrict__ rays_o,
                const float* __restrict__ rays_d,
                const float* __restrict__ t_starts,
                const float* __restrict__ t_ends,
                const int*   __restrict__ ray_idx,
                const float* __restrict__ tab_d,
                const float* __restrict__ tab_c,
                const float* __restrict__ w_d1,
                const float* __restrict__ w_d2,
                const float* __restrict__ w_c1,
                const float* __restrict__ w_c2,
                float* __restrict__ out)
{
    __shared__ __align__(16) float s_wd1[DIN * HDIM];
    __shared__ __align__(16) float s_wc1[DIN * HDIM];
    __shared__ __align__(16) float s_wd2[HDIM];
    __shared__ __align__(16) float s_wc2[HDIM * 3];

    const int lane = threadIdx.x;
    for (int i = lane; i < DIN * HDIM; i += 64) { s_wd1[i] = w_d1[i]; s_wc1[i] = w_c1[i]; }
    if (lane < HDIM) s_wd2[lane] = w_d2[lane];
    for (int i = lane; i < HDIM * 3; i += 64) s_wc2[i] = w_c2[i];
    __syncthreads();

    const int r = blockIdx.x;

    // lower_bound(ray_idx, r) / lower_bound(ray_idx, r+1) on sorted array
    int lo = 0, hi = NSAMP;
    while (lo < hi) { int m = (lo + hi) >> 1; if (ray_idx[m] < r) lo = m + 1; else hi = m; }
    const int start = lo;
    hi = NSAMP;
    while (lo < hi) { int m = (lo + hi) >> 1; if (ray_idx[m] <= r) lo = m + 1; else hi = m; }
    const int end = lo;

    const float ox = rays_o[3 * r + 0], oy = rays_o[3 * r + 1], oz = rays_o[3 * r + 2];
    const float dx = rays_d[3 * r + 0], dy = rays_d[3 * r + 1], dz = rays_d[3 * r + 2];

    float carry = 0.f, accw = 0.f, cr = 0.f, cg = 0.f, cb = 0.f;

    for (int base = start; base < end; base += 64) {
        const int i = base + lane;
        const bool valid = i < end;
        float sv = 0.f, R = 0.f, G = 0.f, B = 0.f;
        if (valid) {
            const float ts = t_starts[i], te = t_ends[i];
            const float tm = 0.5f * (ts + te);
            const float x01x = clamp01f((ox + dx * tm + 1.f) * 0.5f);
            const float x01y = clamp01f((oy + dy * tm + 1.f) * 0.5f);
            const float x01z = clamp01f((oz + dz * tm + 1.f) * 0.5f);

            float hb[HDIM];

            // ---------------- density pass ----------------
            #pragma unroll
            for (int j = 0; j < HDIM; ++j) hb[j] = 0.f;
            #pragma unroll
            for (int l = 0; l < NLEV; ++l) {
                const float res1 = (float)((16 << l) - 1);
                const float px = x01x * res1, py = x01y * res1, pz = x01z * res1;
                const float fxf = floorf(px), fyf = floorf(py), fzf = floorf(pz);
                const uint32_t ix = (uint32_t)fxf, iy = (uint32_t)fyf, iz = (uint32_t)fzf;
                const float fx = px - fxf, fy = py - fyf, fz = pz - fzf;
                const uint32_t hx0 = ix, hx1 = ix + 1u;
                const uint32_t hy0 = iy * 2654435761u, hy1 = hy0 + 2654435761u;
                const uint32_t hz0 = iz * 805459861u,  hz1 = hz0 + 805459861u;
                const float* td = tab_d + (size_t)l * (TSZ * 2);
                float a0 = 0.f, a1 = 0.f;
                #pragma unroll
                for (int c = 0; c < 8; ++c) {
                    const uint32_t h = ((c & 1) ? hx1 : hx0) ^ ((c & 2) ? hy1 : hy0) ^ ((c & 4) ? hz1 : hz0);
                    const float w = ((c & 1) ? fx : 1.f - fx) * ((c & 2) ? fy : 1.f - fy) * ((c & 4) ? fz : 1.f - fz);
                    const float2 v = *(const float2*)(td + (size_t)((h & TMASK) * 2u));
                    a0 += w * v.x; a1 += w * v.y;
                }
                #pragma unroll
                for (int j = 0; j < HDIM; j += 4) {
                    const float4 w0 = *(const float4*)(s_wd1 + (2 * l + 0) * HDIM + j);
                    const float4 w1 = *(const float4*)(s_wd1 + (2 * l + 1) * HDIM + j);
                    hb[j + 0] += a0 * w0.x + a1 * w1.x;
                    hb[j + 1] += a0 * w0.y + a1 * w1.y;
                    hb[j + 2] += a0 * w0.z + a1 * w1.z;
                    hb[j + 3] += a0 * w0.w + a1 * w1.w;
                }
            }
            float dotv = 0.f;
            #pragma unroll
            for (int j = 0; j < HDIM; ++j) dotv += fmaxf(hb[j], 0.f) * s_wd2[j];
            sv = __expf(dotv) * (te - ts);

            // ---------------- color pass ----------------
            #pragma unroll
            for (int j = 0; j < HDIM; ++j) hb[j] = 0.f;
            #pragma unroll
            for (int l = 0; l < NLEV; ++l) {
                const float res1 = (float)((16 << l) - 1);
                const float px = x01x * res1, py = x01y * res1, pz = x01z * res1;
                const float fxf = floorf(px), fyf = floorf(py), fzf = floorf(pz);
                const uint32_t ix = (uint32_t)fxf, iy = (uint32_t)fyf, iz = (uint32_t)fzf;
                const float fx = px - fxf, fy = py - fyf, fz = pz - fzf;
                const uint32_t hx0 = ix, hx1 = ix + 1u;
                const uint32_t hy0 = iy * 2654435761u, hy1 = hy0 + 2654435761u;
                const uint32_t hz0 = iz * 805459861u,  hz1 = hz0 + 805459861u;
                const float* tc = tab_c + (size_t)l * (TSZ * 2);
                float a0 = 0.f, a1 = 0.f;
                #pragma unroll
                for (int c = 0; c < 8; ++c) {
                    const uint32_t h = ((c & 1) ? hx1 : hx0) ^ ((c & 2) ? hy1 : hy0) ^ ((c & 4) ? hz1 : hz0);
                    const float w = ((c & 1) ? fx : 1.f - fx) * ((c & 2) ? fy : 1.f - fy) * ((c & 4) ? fz : 1.f - fz);
                    const float2 v = *(const float2*)(tc + (size_t)((h & TMASK) * 2u));
                    a0 += w * v.x; a1 += w * v.y;
                }
                #pragma unroll
                for (int j = 0; j < HDIM; j += 4) {
                    const float4 w0 = *(const float4*)(s_wc1 + (2 * l + 0) * HDIM + j);
                    const float4 w1 = *(const float4*)(s_wc1 + (2 * l + 1) * HDIM + j);
                    hb[j + 0] += a0 * w0.x + a1 * w1.x;
                    hb[j + 1] += a0 * w0.y + a1 * w1.y;
                    hb[j + 2] += a0 * w0.z + a1 * w1.z;
                    hb[j + 3] += a0 * w0.w + a1 * w1.w;
                }
            }
            float pr = 0.f, pg = 0.f, pb = 0.f;
            #pragma unroll
            for (int j = 0; j < HDIM; ++j) {
                const float hj = fmaxf(hb[j], 0.f);
                pr += hj * s_wc2[3 * j + 0];
                pg += hj * s_wc2[3 * j + 1];
                pb += hj * s_wc2[3 * j + 2];
            }
            R = 1.f / (1.f + __expf(-pr));
            G = 1.f / (1.f + __expf(-pg));
            B = 1.f / (1.f + __expf(-pb));
        }

        // wave-wide inclusive scan of sv (64 lanes)
        float incl = sv;
        #pragma unroll
        for (int off = 1; off < 64; off <<= 1) {
            float t = __shfl_up(incl, off);
            if (lane >= off) incl += t;
        }
        const float e = carry + (incl - sv);      // exclusive cumsum within ray
        const float w = valid ? (1.f - __expf(-sv)) * __expf(-e) : 0.f;
        accw += w; cr += w * R; cg += w * G; cb += w * B;
        carry += __shfl(incl, 63);
    }

    // wave reduction of the four accumulators
    #pragma unroll
    for (int off = 32; off > 0; off >>= 1) {
        accw += __shfl_down(accw, off);
        cr   += __shfl_down(cr, off);
        cg   += __shfl_down(cg, off);
        cb   += __shfl_down(cb, off);
    }

    if (lane == 0) {
        const float bgw = 1.f - accw;   // BG_COLOR = 1.0
        out[0 * HW_NRAYS + r] = clamp01f(cr + bgw);
        out[1 * HW_NRAYS + r] = clamp01f(cg + bgw);
        out[2 * HW_NRAYS + r] = clamp01f(cb + bgw);
        out[3 * HW_NRAYS + r] = clamp01f(accw);
    }
}

extern "C" void kernel_launch(void* const* d_in, const int* in_sizes, int n_in,
                              void* d_out, int out_size, void* d_ws, size_t ws_size,
                              hipStream_t stream) {
    const float* rays_o        = (const float*)d_in[0];
    const float* rays_d        = (const float*)d_in[1];
    const float* t_starts      = (const float*)d_in[2];
    const float* t_ends        = (const float*)d_in[3];
    const int*   ray_indices   = (const int*)d_in[4];
    const float* table_density = (const float*)d_in[5];
    const float* table_color   = (const float*)d_in[6];
    const float* w_d1          = (const float*)d_in[7];
    const float* w_d2          = (const float*)d_in[8];
    const float* w_c1          = (const float*)d_in[9];
    const float* w_c2          = (const float*)d_in[10];
    float* outp = (float*)d_out;

    hipLaunchKernelGGL(ngp_render, dim3(HW_NRAYS), dim3(64), 0, stream,
                       rays_o, rays_d, t_starts, t_ends, ray_indices,
                       table_density, table_color, w_d1, w_d2, w_c1, w_c2, outp);
}

// Round 3
// 1416.387 us; speedup vs baseline: 7.3609x; 4.9845x over previous
//
#include <hip/hip_runtime.h>
#include <cstdint>
#include <cstddef>

#define HW_NRAYS 16384
#define NSAMP    (1 << 21)
#define NLEV     12
#define TSZ      (1 << 19)
#define TMASK    (TSZ - 1)
#define DIN      24
#define HDIM     32
#define WS_TAB_QWORDS (NLEV * TSZ)
#define WS_TAB_BYTES  ((size_t)WS_TAB_QWORDS * 8)

__device__ __forceinline__ float clamp01f(float v) { return fminf(fmaxf(v, 0.f), 1.f); }

__device__ __forceinline__ uint32_t rne_bf16_lo(uint32_t u) {
    // round-to-nearest-even f32 -> bf16, result in low 16 bits
    return (u + 0x7fffu + ((u >> 16) & 1u)) >> 16;
}

// Pack (d0,d1,c0,c1) per hash entry into 4x bf16 (8 bytes): one gather feeds both MLPs.
__global__ __launch_bounds__(256)
void ngp_pack_tables(const float2* __restrict__ tab_d,
                     const float2* __restrict__ tab_c,
                     uint2* __restrict__ ws_tab)
{
    const int stride = gridDim.x * blockDim.x;
    for (int i = blockIdx.x * blockDim.x + threadIdx.x; i < WS_TAB_QWORDS; i += stride) {
        const float2 d = tab_d[i];
        const float2 c = tab_c[i];
        const uint32_t w0 = rne_bf16_lo(__float_as_uint(d.x)) | (rne_bf16_lo(__float_as_uint(d.y)) << 16);
        const uint32_t w1 = rne_bf16_lo(__float_as_uint(c.x)) | (rne_bf16_lo(__float_as_uint(c.y)) << 16);
        ws_tab[i] = make_uint2(w0, w1);
    }
}

template <bool ILV>
__global__ __launch_bounds__(64, 4)
void ngp_render(const float* __restrict__ rays_o,
                const float* __restrict__ rays_d,
                const float* __restrict__ t_starts,
                const float* __restrict__ t_ends,
                const int*   __restrict__ ray_idx,
                const float* __restrict__ tab_d,
                const float* __restrict__ tab_c,
                const uint2* __restrict__ ws_tab,
                const float* __restrict__ w_d1,
                const float* __restrict__ w_d2,
                const float* __restrict__ w_c1,
                const float* __restrict__ w_c2,
                float* __restrict__ out)
{
    __shared__ __align__(16) float s_wd1[DIN * HDIM];
    __shared__ __align__(16) float s_wc1[DIN * HDIM];
    __shared__ __align__(16) float s_wd2[HDIM];
    __shared__ __align__(16) float s_wc2[HDIM * 3];

    const int lane = threadIdx.x;
    for (int i = lane; i < DIN * HDIM; i += 64) { s_wd1[i] = w_d1[i]; s_wc1[i] = w_c1[i]; }
    if (lane < HDIM) s_wd2[lane] = w_d2[lane];
    for (int i = lane; i < HDIM * 3; i += 64) s_wc2[i] = w_c2[i];
    __syncthreads();

    const int r = blockIdx.x;

    // lower_bound(ray_idx, r) / lower_bound(ray_idx, r+1) on sorted array
    int lo = 0, hi = NSAMP;
    while (lo < hi) { int m = (lo + hi) >> 1; if (ray_idx[m] < r) lo = m + 1; else hi = m; }
    const int start = lo;
    hi = NSAMP;
    while (lo < hi) { int m = (lo + hi) >> 1; if (ray_idx[m] <= r) lo = m + 1; else hi = m; }
    const int end = lo;

    const float ox = rays_o[3 * r + 0], oy = rays_o[3 * r + 1], oz = rays_o[3 * r + 2];
    const float dx = rays_d[3 * r + 0], dy = rays_d[3 * r + 1], dz = rays_d[3 * r + 2];

    float carry = 0.f, accw = 0.f, cr = 0.f, cg = 0.f, cb = 0.f;

    for (int base = start; base < end; base += 64) {
        const int i = base + lane;
        const bool valid = i < end;
        float sv = 0.f, R = 0.f, G = 0.f, B = 0.f;
        if (valid) {
            const float ts = t_starts[i], te = t_ends[i];
            const float tm = 0.5f * (ts + te);
            const float x01x = clamp01f((ox + dx * tm + 1.f) * 0.5f);
            const float x01y = clamp01f((oy + dy * tm + 1.f) * 0.5f);
            const float x01z = clamp01f((oz + dz * tm + 1.f) * 0.5f);

            float hbD[HDIM], hbC[HDIM];
            #pragma unroll
            for (int j = 0; j < HDIM; ++j) { hbD[j] = 0.f; hbC[j] = 0.f; }

            #pragma unroll 1
            for (int l = 0; l < NLEV; ++l) {
                const float res1 = (float)((16 << l) - 1);
                const float px = x01x * res1, py = x01y * res1, pz = x01z * res1;
                const float fxf = floorf(px), fyf = floorf(py), fzf = floorf(pz);
                const uint32_t ix = (uint32_t)fxf, iy = (uint32_t)fyf, iz = (uint32_t)fzf;
                const float fx = px - fxf, fy = py - fyf, fz = pz - fzf;
                const uint32_t hx0 = ix, hx1 = ix + 1u;
                const uint32_t hy0 = iy * 2654435761u, hy1 = hy0 + 2654435761u;
                const uint32_t hz0 = iz * 805459861u,  hz1 = hz0 + 805459861u;

                float a0 = 0.f, a1 = 0.f, b0 = 0.f, b1 = 0.f;
                if constexpr (ILV) {
                    const uint2* tl = ws_tab + (size_t)l * TSZ;
                    #pragma unroll
                    for (int c = 0; c < 8; ++c) {
                        const uint32_t h = ((c & 1) ? hx1 : hx0) ^ ((c & 2) ? hy1 : hy0) ^ ((c & 4) ? hz1 : hz0);
                        const float w = ((c & 1) ? fx : 1.f - fx) * ((c & 2) ? fy : 1.f - fy) * ((c & 4) ? fz : 1.f - fz);
                        const uint2 v = tl[h & TMASK];
                        const float d0 = __uint_as_float(v.x << 16);
                        const float d1 = __uint_as_float(v.x & 0xffff0000u);
                        const float c0 = __uint_as_float(v.y << 16);
                        const float c1 = __uint_as_float(v.y & 0xffff0000u);
                        a0 += w * d0; a1 += w * d1; b0 += w * c0; b1 += w * c1;
                    }
                } else {
                    const float* td = tab_d + (size_t)l * (TSZ * 2);
                    const float* tc = tab_c + (size_t)l * (TSZ * 2);
                    #pragma unroll
                    for (int c = 0; c < 8; ++c) {
                        const uint32_t h = ((c & 1) ? hx1 : hx0) ^ ((c & 2) ? hy1 : hy0) ^ ((c & 4) ? hz1 : hz0);
                        const float w = ((c & 1) ? fx : 1.f - fx) * ((c & 2) ? fy : 1.f - fy) * ((c & 4) ? fz : 1.f - fz);
                        const float2 vd = *(const float2*)(td + (size_t)((h & TMASK) * 2u));
                        const float2 vc = *(const float2*)(tc + (size_t)((h & TMASK) * 2u));
                        a0 += w * vd.x; a1 += w * vd.y; b0 += w * vc.x; b1 += w * vc.y;
                    }
                }

                const float* wd0 = s_wd1 + (2 * l + 0) * HDIM;
                const float* wd1r = s_wd1 + (2 * l + 1) * HDIM;
                const float* wc0 = s_wc1 + (2 * l + 0) * HDIM;
                const float* wc1r = s_wc1 + (2 * l + 1) * HDIM;
                #pragma unroll
                for (int j = 0; j < HDIM; j += 4) {
                    const float4 u0 = *(const float4*)(wd0 + j);
                    const float4 u1 = *(const float4*)(wd1r + j);
                    hbD[j + 0] += a0 * u0.x + a1 * u1.x;
                    hbD[j + 1] += a0 * u0.y + a1 * u1.y;
                    hbD[j + 2] += a0 * u0.z + a1 * u1.z;
                    hbD[j + 3] += a0 * u0.w + a1 * u1.w;
                    const float4 v0 = *(const float4*)(wc0 + j);
                    const float4 v1 = *(const float4*)(wc1r + j);
                    hbC[j + 0] += b0 * v0.x + b1 * v1.x;
                    hbC[j + 1] += b0 * v0.y + b1 * v1.y;
                    hbC[j + 2] += b0 * v0.z + b1 * v1.z;
                    hbC[j + 3] += b0 * v0.w + b1 * v1.w;
                }
            }

            float dotv = 0.f;
            #pragma unroll
            for (int j = 0; j < HDIM; ++j) dotv += fmaxf(hbD[j], 0.f) * s_wd2[j];
            sv = __expf(dotv) * (te - ts);

            float pr = 0.f, pg = 0.f, pb = 0.f;
            #pragma unroll
            for (int j = 0; j < HDIM; ++j) {
                const float hj = fmaxf(hbC[j], 0.f);
                pr += hj * s_wc2[3 * j + 0];
                pg += hj * s_wc2[3 * j + 1];
                pb += hj * s_wc2[3 * j + 2];
            }
            R = 1.f / (1.f + __expf(-pr));
            G = 1.f / (1.f + __expf(-pg));
            B = 1.f / (1.f + __expf(-pb));
        }

        // wave-wide inclusive scan of sv (64 lanes)
        float incl = sv;
        #pragma unroll
        for (int off = 1; off < 64; off <<= 1) {
            float t = __shfl_up(incl, off);
            if (lane >= off) incl += t;
        }
        const float e = carry + (incl - sv);      // exclusive cumsum within ray
        const float w = valid ? (1.f - __expf(-sv)) * __expf(-e) : 0.f;
        accw += w; cr += w * R; cg += w * G; cb += w * B;
        carry += __shfl(incl, 63);
    }

    #pragma unroll
    for (int off = 32; off > 0; off >>= 1) {
        accw += __shfl_down(accw, off);
        cr   += __shfl_down(cr, off);
        cg   += __shfl_down(cg, off);
        cb   += __shfl_down(cb, off);
    }

    if (lane == 0) {
        const float bgw = 1.f - accw;   // BG_COLOR = 1.0
        out[0 * HW_NRAYS + r] = clamp01f(cr + bgw);
        out[1 * HW_NRAYS + r] = clamp01f(cg + bgw);
        out[2 * HW_NRAYS + r] = clamp01f(cb + bgw);
        out[3 * HW_NRAYS + r] = clamp01f(accw);
    }
}

extern "C" void kernel_launch(void* const* d_in, const int* in_sizes, int n_in,
                              void* d_out, int out_size, void* d_ws, size_t ws_size,
                              hipStream_t stream) {
    const float* rays_o        = (const float*)d_in[0];
    const float* rays_d        = (const float*)d_in[1];
    const float* t_starts      = (const float*)d_in[2];
    const float* t_ends        = (const float*)d_in[3];
    const int*   ray_indices   = (const int*)d_in[4];
    const float* table_density = (const float*)d_in[5];
    const float* table_color   = (const float*)d_in[6];
    const float* w_d1          = (const float*)d_in[7];
    const float* w_d2          = (const float*)d_in[8];
    const float* w_c1          = (const float*)d_in[9];
    const float* w_c2          = (const float*)d_in[10];
    float* outp = (float*)d_out;

    if (ws_size >= WS_TAB_BYTES) {
        uint2* ws_tab = (uint2*)d_ws;
        hipLaunchKernelGGL(ngp_pack_tables, dim3(1024), dim3(256), 0, stream,
                           (const float2*)table_density, (const float2*)table_color, ws_tab);
        hipLaunchKernelGGL((ngp_render<true>), dim3(HW_NRAYS), dim3(64), 0, stream,
                           rays_o, rays_d, t_starts, t_ends, ray_indices,
                           table_density, table_color, ws_tab,
                           w_d1, w_d2, w_c1, w_c2, outp);
    } else {
        hipLaunchKernelGGL((ngp_render<false>), dim3(HW_NRAYS), dim3(64), 0, stream,
                           rays_o, rays_d, t_starts, t_ends, ray_indices,
                           table_density, table_color, (const uint2*)nullptr,
                           w_d1, w_d2, w_c1, w_c2, outp);
    }
}